// Round 9
// baseline (254.923 us; speedup 1.0000x reference)
//
#include <hip/hip_runtime.h>
#include <type_traits>

// ============================================================================
// MHA: B=4, S=2048, D=1024, H=16, hd=64. fp32 I/O, bf16 MFMA compute.
// Round 17: FIX of R16's race (single change). R16 NaN cause: ph0/ph2 issued
//   ds_reads of half H(t,.) right after this wave's vmcnt(6) with NO barrier
//   between drain and reads — vmcnt is per-wave, so rows staged by the other
//   7 waves were not guaranteed visible (same hole in the prologue). Fix =
//   m201/R11 ordering: every drain is vmcnt -> BARRIER -> reads:
//     prologue: stage H(0,0),H(0,1),H(1,0); vmcnt(6); barrier
//     iter t: ph0 reads half0 (safe via prev vmcnt+barrier); stage H(t+1,1);
//                 bar; prio1 8-MFMA prio0; bar
//             ph1 reads half0 i23; bar; 8-MFMA; vmcnt(6) [drain H(t,1)]; bar
//             ph2 reads half1; stage H(t+2,0); bar; 8-MFMA; bar
//             ph3 reads half1 i23; bar; 8-MFMA; vmcnt(6) [drain H(t+1,0)]; bar
//     tail: t=14 ph3 vmcnt(3); t=15 ph1 vmcnt(0), ph3 none. Hand-simulated
//     per-thread outstanding counts (3 loads/half): 9->6 steady, never 0
//     until the final tile (T4). Overwrite safety: each stage dest's last
//     reads were consumed >=1 barrier earlier.
//   Geometry unchanged from R16: BM=128 BN=256 BK=64, 512thr/8 waves (2Mx4N),
//   wave 64x64 acc[4][4], LDS 96KB ([2buf][2half] per operand), 1 block/CU.
//   Grids: QKV (64,12)=768 = 3 rounds; out-proj (64,4)=256 = 1 round.
//   Fallback if null/fail: R15 (242.6us, passed).
// Kept (counter-verified): attn8 (8-wave shared staging, 2 blocks/CU,
// balanced CU pairing), fused cvt_xw, global_load_lds staging, fused
// V-transpose, S^T packed P-stores, no-max softmax, Q pre-scale, raw
// v_exp_f32, ring-verified 0-conflict LDS swizzle.
// Fragment layouts (m89/m91-verified):
//    A-frag:  A[m = lane&15][k = (lane>>4)*8 + j]
//    B-frag:  B[n = lane&15][k = (lane>>4)*8 + j]
//    C/D:     C[row(m) = (lane>>4)*4 + reg][col(n) = lane&15]
// ============================================================================

typedef unsigned short u16;
typedef __attribute__((ext_vector_type(8))) short s8;   // 8 bf16 (16B)
typedef __attribute__((ext_vector_type(4))) float f4;

#if __has_builtin(__builtin_amdgcn_exp2f)
#define EXP2(x) __builtin_amdgcn_exp2f(x)   // raw v_exp_f32, no ocml wrapper
#else
#define EXP2(x) exp2f(x)
#endif

__device__ __forceinline__ u16 f2bf(float f) {
    union { float f; unsigned u; } v; v.f = f;
    unsigned r = v.u + 0x7fffu + ((v.u >> 16) & 1u);   // RNE
    return (u16)(r >> 16);
}

// pack two fp32 -> two bf16 (truncation) in one v_perm: low u16 = a, high = b
__device__ __forceinline__ unsigned pack_bf2(float a, float b) {
    return __builtin_amdgcn_perm(__float_as_uint(b), __float_as_uint(a),
                                 0x07060302u);
}

// async 16B global -> LDS (wave-uniform lds base; HW scatters lane*16)
__device__ __forceinline__ void cp16(const void* g, void* l) {
    __builtin_amdgcn_global_load_lds(
        (const __attribute__((address_space(1))) unsigned int*)g,
        (__attribute__((address_space(3))) unsigned int*)l, 16, 0, 0);
}

__device__ __forceinline__ s8 load8f(const float* p) {
    const float4 lo = *(const float4*)p;
    const float4 hi = *(const float4*)(p + 4);
    s8 r;
    r[0] = (short)f2bf(lo.x); r[1] = (short)f2bf(lo.y);
    r[2] = (short)f2bf(lo.z); r[3] = (short)f2bf(lo.w);
    r[4] = (short)f2bf(hi.x); r[5] = (short)f2bf(hi.y);
    r[6] = (short)f2bf(hi.z); r[7] = (short)f2bf(hi.w);
    return r;
}

// ---------------------------------------------------------------------------
// fp32 -> bf16 bulk convert (RNE), n8 groups of 8
// ---------------------------------------------------------------------------
__global__ __launch_bounds__(256)
void f32_to_bf16(const float* __restrict__ in, u16* __restrict__ out, int n8)
{
    const int i = blockIdx.x * 256 + threadIdx.x;
    if (i < n8) *(s8*)(out + (size_t)i * 8) = load8f(in + (size_t)i * 8);
}

// fused x + {wq,wk,wv} conversion: one dispatch.
// x: 1048576 groups of 8; weights: 3 x 131072 groups. grid = 5632 x 256.
__global__ __launch_bounds__(256)
void cvt_xw(const float* __restrict__ x,
            const float* __restrict__ wq, const float* __restrict__ wk,
            const float* __restrict__ wv,
            u16* __restrict__ Xb, u16* __restrict__ Wqkv)
{
    const int i = blockIdx.x * 256 + threadIdx.x;
    if (i < 1048576) {
        *(s8*)(Xb + (size_t)i * 8) = load8f(x + (size_t)i * 8);
    } else {
        const int j = i - 1048576;
        const int sel = j >> 17;            // 0..2 (131072 = 2^17 groups)
        const int wi  = j & 131071;
        const float* src = (sel == 0) ? wq : ((sel == 1) ? wk : wv);
        *(s8*)(Wqkv + (size_t)sel * 1048576 + (size_t)wi * 8) =
            load8f(src + (size_t)wi * 8);
    }
}

// ---------------------------------------------------------------------------
// C = A @ W^T, all-bf16. 512 thr / 8 waves (2M x 4N). BM=128 BN=256 BK=64.
// Per-wave output 64x64 (acc[4][4]). LDS = A[2][2][128x32] + B[2][2][256x32]
// = 96KB -> 1 block/CU. Counted-vmcnt half-tile pipeline (see file header).
// A: [M,K] bf16. W per 256-col block from {W0,W1,W2} ([1024,K] bf16).
// mode 0: C0 (scaled by cscale). 1: C1. 2: VT transposed per-head:
//   VT[(b*16+h)*64+d][2048], b=row>>11, s=row&2047.
// 32-elem rows (64B); swizzle: stage G-col ((lane&3)^((lane>>3)&3))*8 at
// row lane>>2; read chunk (quad ^ ((l16>>1)&3))*8  [ring-verified, 0 confl].
// ---------------------------------------------------------------------------
template<typename TC>
__global__ __launch_bounds__(512)
void gemm8p(const u16* __restrict__ A,
            const u16* __restrict__ W0, const u16* __restrict__ W1,
            const u16* __restrict__ W2,
            TC* __restrict__ C0, TC* __restrict__ C1,
            u16* __restrict__ VT, int K, float cscale)
{
    __shared__ u16 As[2][2][128 * 32];   // [buf][half] 32 KB
    __shared__ u16 Bs[2][2][256 * 32];   // [buf][half] 64 KB

    const int t  = threadIdx.x;
    const int bm = blockIdx.x;
    const int nglob = blockIdx.y * 256;

    const u16* W; int nloc, mode;
    if (nglob < 1024)      { W = W0; nloc = nglob;        mode = 0; }
    else if (nglob < 2048) { W = W1; nloc = nglob - 1024; mode = 1; }
    else                   { W = W2; nloc = nglob - 2048; mode = 2; }

    const int lane = t & 63, w = t >> 6;      // 8 waves
    const int wr = w >> 2, wc = w & 3;        // 2M x 4N
    const int quad = lane >> 4, l16 = lane & 15;

    // staging: 1 cp16/wave = 1KB = 16 rows x 64B. row = lane>>2,
    // src col chunk = ((lane&3)^((lane>>3)&3)) (LDS[r][c]=G[r][c^((r>>1)&3)])
    const int sw = ((lane & 3) ^ ((lane >> 3) & 3)) * 8;   // elem offset
    const int r16 = lane >> 2;                              // 0..15
    const u16* Ag = A + (size_t)(bm * 128 + 16 * w + r16) * K + sw;  // 16 rows/wave
    const u16* Wg = W + (size_t)(nloc + 32 * w + r16) * K + sw;      // 32 rows/wave
    const int ldsA = (16 * w) * 32;           // wave-uniform dests
    const int ldsB0 = (32 * w) * 32;
    const int ldsB1 = (32 * w + 16) * 32;

    // stage half (kt, hf): A 1 cp16 + B 2 cp16 = 3 loads per thread
    auto stageH = [&](int buf, int kt, int hf) {
        const int k0 = kt * 64 + hf * 32;
        cp16(Ag + k0, &As[buf][hf][ldsA]);
        cp16(Wg + k0, &Bs[buf][hf][ldsB0]);
        cp16(Wg + (size_t)16 * K + k0, &Bs[buf][hf][ldsB1]);
    };

    // frag-read chunk offset
    const int ca = (quad ^ ((l16 >> 1) & 3)) * 8;
    #define ARD(i, kk) (*(const s8*)&As[cur][kk][(wr * 64 + (i) * 16 + l16) * 32 + ca])
    #define BRD(j, kk) (*(const s8*)&Bs[cur][kk][(wc * 64 + (j) * 16 + l16) * 32 + ca])

    f4 acc[4][4];
    #pragma unroll
    for (int i = 0; i < 4; i++)
        #pragma unroll
        for (int j = 0; j < 4; j++)
            acc[i][j] = (f4){0.f, 0.f, 0.f, 0.f};

    const int NK = K >> 6;                    // 16
    // prologue: 3 halves in flight; H(0,0) landed + barrier BEFORE any read
    stageH(0, 0, 0);
    stageH(0, 0, 1);
    stageH(1, 1, 0);
    asm volatile("s_waitcnt vmcnt(6)" ::: "memory");
    __builtin_amdgcn_s_barrier();

    int cur = 0;
    for (int kt = 0; kt < NK; ++kt) {
        const bool m1 = (kt + 1 < NK);        // stage H(t+1,1)?
        const bool m2 = (kt + 2 < NK);        // stage H(t+2,0)?
        s8 af[4], bf[4];

        // ---- ph0: kk=0, i01 (half0 landed: prev vmcnt+barrier) ----
        #pragma unroll
        for (int i = 0; i < 2; i++) af[i] = ARD(i, 0);
        #pragma unroll
        for (int j = 0; j < 4; j++) bf[j] = BRD(j, 0);
        if (m1) stageH(cur ^ 1, kt + 1, 1);
        __builtin_amdgcn_s_barrier();
        __builtin_amdgcn_s_setprio(1);
        #pragma unroll
        for (int i = 0; i < 2; i++)
            #pragma unroll
            for (int j = 0; j < 4; j++)
                acc[i][j] = __builtin_amdgcn_mfma_f32_16x16x32_bf16(
                                af[i], bf[j], acc[i][j], 0, 0, 0);
        __builtin_amdgcn_s_setprio(0);
        __builtin_amdgcn_s_barrier();

        // ---- ph1: kk=0, i23; end: drain H(t,1) then barrier ----
        #pragma unroll
        for (int i = 2; i < 4; i++) af[i] = ARD(i, 0);
        __builtin_amdgcn_s_barrier();
        __builtin_amdgcn_s_setprio(1);
        #pragma unroll
        for (int i = 2; i < 4; i++)
            #pragma unroll
            for (int j = 0; j < 4; j++)
                acc[i][j] = __builtin_amdgcn_mfma_f32_16x16x32_bf16(
                                af[i], bf[j], acc[i][j], 0, 0, 0);
        __builtin_amdgcn_s_setprio(0);
        if (m1) asm volatile("s_waitcnt vmcnt(6)" ::: "memory");
        else    asm volatile("s_waitcnt vmcnt(0)" ::: "memory");
        __builtin_amdgcn_s_barrier();

        // ---- ph2: kk=1, i01 (half1 landed via ph1 vmcnt+barrier) ----
        #pragma unroll
        for (int i = 0; i < 2; i++) af[i] = ARD(i, 1);
        #pragma unroll
        for (int j = 0; j < 4; j++) bf[j] = BRD(j, 1);
        if (m2) stageH(cur, kt + 2, 0);   // cur buf half0: reads done ph0/ph1
        __builtin_amdgcn_s_barrier();
        __builtin_amdgcn_s_setprio(1);
        #pragma unroll
        for (int i = 0; i < 2; i++)
            #pragma unroll
            for (int j = 0; j < 4; j++)
                acc[i][j] = __builtin_amdgcn_mfma_f32_16x16x32_bf16(
                                af[i], bf[j], acc[i][j], 0, 0, 0);
        __builtin_amdgcn_s_setprio(0);
        __builtin_amdgcn_s_barrier();

        // ---- ph3: kk=1, i23; end: drain H(t+1,0) then barrier ----
        #pragma unroll
        for (int i = 2; i < 4; i++) af[i] = ARD(i, 1);
        __builtin_amdgcn_s_barrier();
        __builtin_amdgcn_s_setprio(1);
        #pragma unroll
        for (int i = 2; i < 4; i++)
            #pragma unroll
            for (int j = 0; j < 4; j++)
                acc[i][j] = __builtin_amdgcn_mfma_f32_16x16x32_bf16(
                                af[i], bf[j], acc[i][j], 0, 0, 0);
        __builtin_amdgcn_s_setprio(0);
        if (m2)      asm volatile("s_waitcnt vmcnt(6)" ::: "memory");
        else if (m1) asm volatile("s_waitcnt vmcnt(3)" ::: "memory");
        __builtin_amdgcn_s_barrier();

        cur ^= 1;
    }
    #undef ARD
    #undef BRD

    if (mode == 2) {
        // V -> Vt[(b*16+h)*64+d][s], 4 consecutive s per lane -> uint2
        #pragma unroll
        for (int i = 0; i < 4; i++) {
            const int row0 = bm * 128 + wr * 64 + i * 16 + quad * 4;
            const int b = row0 >> 11, s = row0 & 2047;
            #pragma unroll
            for (int j = 0; j < 4; j++) {
                const int n = nloc + wc * 64 + j * 16 + l16;   // 0..1023
                const int h = n >> 6, d = n & 63;
                unsigned lo = ((unsigned)f2bf(acc[i][j][1]) << 16) | f2bf(acc[i][j][0]);
                unsigned hi = ((unsigned)f2bf(acc[i][j][3]) << 16) | f2bf(acc[i][j][2]);
                *(uint2*)(VT + ((size_t)((b * 16 + h) * 64 + d)) * 2048 + s) =
                    make_uint2(lo, hi);
            }
        }
    } else {
        TC* C = (mode == 0) ? C0 : C1;
        const float cs = (mode == 0) ? cscale : 1.0f;
        #pragma unroll
        for (int i = 0; i < 4; i++) {
            const int row = bm * 128 + wr * 64 + i * 16 + quad * 4;
            #pragma unroll
            for (int j = 0; j < 4; j++) {
                const int col = nloc + wc * 64 + j * 16 + l16;
                #pragma unroll
                for (int r = 0; r < 4; r++) {
                    const float val = acc[i][j][r] * cs;
                    if constexpr (std::is_same<TC, float>::value)
                        C[(size_t)(row + r) * 1024 + col] = val;
                    else
                        C[(size_t)(row + r) * 1024 + col] = f2bf(val);
                }
            }
        }
    }
}

// ---------------------------------------------------------------------------
// Flash-style causal attention, no-max softmax, one q32 granule per wave.
// Block: 512 threads = 8 waves sharing one K/V staging pipeline (2 cp16/
// wave/tile). Grid (64 bh, 8 y), p = y<4 ? 7-y : y-4 (heavy blocks first;
// (c, c+256) CU pairs sum to 36 staged tiles on every CU -> balanced).
// Wave w owns q32 = 8p+w; ktw = q32/2+1; block stages ktb = 4p+4 tiles.
// LDS 69.6KB -> 2 blocks/CU = 16 waves/CU. K/V dbuf; stage(kt+1) before
// compute(kt). Q,K: [B*S,1024] bf16 (Q pre-scaled by (1/8)log2e).
// Vt: [(b*16+h)*64+d][2048] bf16.  O -> Q's buffer (row/col disjoint, safe).
// ---------------------------------------------------------------------------
#define PSTR 72   // Ps row stride elems (144B: 16B-aligned rows)

__global__ __launch_bounds__(512)
void attn8(const u16* __restrict__ Q, const u16* __restrict__ K,
           const u16* __restrict__ Vt, u16* __restrict__ O)
{
    __shared__ u16 Ks[2][64 * 64];      // [s][d] swizzled, double-buffered
    __shared__ u16 Vs[2][64 * 64];      // [d][s] swizzled, double-buffered
    __shared__ u16 Ps[8][32 * PSTR];    // per-wave P [q(32)][kv(64)]

    const int bh = blockIdx.x;          // b*16 + h
    const int yy = blockIdx.y;          // 0..7
    const int p  = (yy < 4) ? (7 - yy) : (yy - 4);   // balanced CU pairing
    const int h  = bh & 15, b = bh >> 4;

    const int t = threadIdx.x, lane = t & 63, w = t >> 6;   // w: 0..7
    const int quad = lane >> 4, l16 = lane & 15;
    const int colH = h * 64;

    const int q32 = 8 * p + w;          // this wave's q granule 0..63
    const int ktw = q32 / 2 + 1;        // wave's kv tile count
    const int ktb = 4 * p + 4;          // block staging count (= max ktw)

    s8 ones;
    for (int e = 0; e < 8; e++) ones[e] = (short)0x3F80;   // bf16 1.0

    // staging coords: each wave stages 8 rows of K and 8 rows of V per tile
    const int vrow = lane >> 3;                    // 0..7
    const int scc  = ((lane & 7) ^ vrow) * 8;      // swizzled chunk
    const int r0   = w * 8 + vrow;                 // row 0..63
    const u16* Kg = K  + ((size_t)b * 2048 + r0) * 1024 + colH + scc;
    const u16* Vg = Vt + ((size_t)(b * 16 + h) * 64 + r0) * 2048 + scc;
    const int klds = (w * 8) * 64;      // wave-uniform LDS dest offset

    auto stageKV = [&](int buf, int kt) {
        cp16(Kg + (size_t)kt * 65536, &Ks[buf][klds]);
        cp16(Vg + kt * 64, &Vs[buf][klds]);
    };

    const size_t rowQ0 = (size_t)b * 2048 + q32 * 32;

    // Q fragments for this wave's 32 rows (A-layout, pre-scaled)
    s8 qf[2][2];
    for (int i = 0; i < 2; i++)
        for (int kk = 0; kk < 2; kk++)
            qf[i][kk] = *(const s8*)&Q[(rowQ0 + i * 16 + l16) * 1024 +
                                       colH + kk * 32 + quad * 8];

    f4 o_acc[2][4];
    f4 l_acc[2];
    for (int i = 0; i < 2; i++) {
        l_acc[i] = (f4){0.f, 0.f, 0.f, 0.f};
        for (int j = 0; j < 4; j++)
            o_acc[i][j] = (f4){0.f, 0.f, 0.f, 0.f};
    }

    stageKV(0, 0);                      // prologue: tile 0 in flight
    int cur = 0;

    for (int kt = 0; kt < ktb; ++kt) {
        __syncthreads();                      // buf[cur] DMA done;
                                              // prev reads of buf^1 done
        if (kt + 1 < ktb) stageKV(cur ^ 1, kt + 1);   // next in flight

        if (kt < ktw) {
            // S^T = K @ Q^T : sa[j][i] kv on C/D rows, q on cols
            f4 sa[4][2];
            for (int j = 0; j < 4; j++)
                for (int i = 0; i < 2; i++)
                    sa[j][i] = (f4){0.f, 0.f, 0.f, 0.f};
            for (int kk = 0; kk < 2; kk++) {
                s8 kf[4];
                for (int j = 0; j < 4; j++)
                    kf[j] = *(const s8*)&Ks[cur][(j * 16 + l16) * 64 +
                                            (((kk * 4 + quad) ^ (l16 & 7)) * 8)];
                for (int j = 0; j < 4; j++)
                    for (int i = 0; i < 2; i++)
                        sa[j][i] = __builtin_amdgcn_mfma_f32_16x16x32_bf16(
                                       kf[j], qf[i][kk], sa[j][i], 0, 0, 0);
            }

            // P = exp2(sa) via raw v_exp_f32; causal mask on last tile
            const bool diag = (kt == ktw - 1);
            for (int i = 0; i < 2; i++) {
                const int q_l = i * 16 + l16;               // local row
                const int q_g = q32 * 32 + q_l;             // global row
                for (int j = 0; j < 4; j++) {
                    const int kv0 = kt * 64 + j * 16 + quad * 4;
                    float p0 = EXP2(sa[j][i][0]);
                    float p1 = EXP2(sa[j][i][1]);
                    float p2 = EXP2(sa[j][i][2]);
                    float p3 = EXP2(sa[j][i][3]);
                    if (diag) {
                        if (kv0 + 0 > q_g) p0 = 0.f;
                        if (kv0 + 1 > q_g) p1 = 0.f;
                        if (kv0 + 2 > q_g) p2 = 0.f;
                        if (kv0 + 3 > q_g) p3 = 0.f;
                    }
                    *(uint2*)&Ps[w][q_l * PSTR + j * 16 + quad * 4] =
                        make_uint2(pack_bf2(p0, p1), pack_bf2(p2, p3));
                }
            }
            // no barrier: Ps[w] wave-private; per-wave DS ops in order

            // O += P @ V ; l += P @ ones
            for (int kk = 0; kk < 2; kk++) {
                s8 pf[2], vf[4];
                for (int i = 0; i < 2; i++)
                    pf[i] = *(const s8*)&Ps[w][(i * 16 + l16) * PSTR +
                                               kk * 32 + quad * 8];
                for (int jd = 0; jd < 4; jd++)
                    vf[jd] = *(const s8*)&Vs[cur][(jd * 16 + l16) * 64 +
                                            (((kk * 4 + quad) ^ (l16 & 7)) * 8)];
                for (int i = 0; i < 2; i++)
                    l_acc[i] = __builtin_amdgcn_mfma_f32_16x16x32_bf16(
                                   pf[i], ones, l_acc[i], 0, 0, 0);
                for (int i = 0; i < 2; i++)
                    for (int jd = 0; jd < 4; jd++)
                        o_acc[i][jd] = __builtin_amdgcn_mfma_f32_16x16x32_bf16(
                                           pf[i], vf[jd], o_acc[i][jd], 0, 0, 0);
            }
        }
        cur ^= 1;
    }

    // epilogue: O /= l, write 32 rows (disjoint rows/cols -> safe to alias
    // Q: only this wave ever touches rows q32*32.. at cols colH..)
    for (int i = 0; i < 2; i++) {
        float rinv[4];
        for (int r = 0; r < 4; r++) rinv[r] = 1.0f / l_acc[i][r];
        for (int jd = 0; jd < 4; jd++)
            for (int r = 0; r < 4; r++) {
                const size_t row = rowQ0 + i * 16 + quad * 4 + r;
                O[row * 1024 + colH + jd * 16 + l16] =
                    f2bf(o_acc[i][jd][r] * rinv[r]);
            }
    }
}

// ---------------------------------------------------------------------------
extern "C" void kernel_launch(void* const* d_in, const int* in_sizes, int n_in,
                              void* d_out, int out_size, void* d_ws, size_t ws_size,
                              hipStream_t stream)
{
    const float* x  = (const float*)d_in[0];
    const float* wq = (const float*)d_in[1];
    const float* wk = (const float*)d_in[2];
    const float* wv = (const float*)d_in[3];
    const float* wo = (const float*)d_in[4];
    float* out = (float*)d_out;

    const size_t MD = (size_t)8192 * 1024;
    const size_t WD = (size_t)1024 * 1024;
    u16* Qb  = (u16*)d_ws;       // Q, later O
    u16* Kb  = Qb + MD;          // K, later wo-bf16
    u16* Vtb = Kb + MD;          // V transposed
    u16* Xb  = Vtb + MD;         // x bf16
    u16* Wqkv = (u16*)d_out;     // wq/wk/wv bf16 scratch (dead before gemm2)
    u16* Ob  = Qb;
    u16* Wob = Kb;

    // 1. fused conversion: x -> Xb, {wq,wk,wv} -> Wqkv (one dispatch)
    cvt_xw<<<5632, 256, 0, stream>>>(x, wq, wk, wv, Xb, Wqkv);

    // 2. QKV projections (V written transposed; Q scaled by (1/8)log2e)
    //    BM=128 -> 64 row-blocks; BN=256 -> 12 col-blocks; 768 = 3 rounds
    gemm8p<u16><<<dim3(64, 12), 512, 0, stream>>>(
        Xb, Wqkv, Wqkv + WD, Wqkv + 2 * WD, Qb, Kb, Vtb, 1024, 0.18033688f);

    // 3. causal attention (O -> Qb); grid (bh, y): same-bh blocks same XCD
    attn8<<<dim3(64, 8), 512, 0, stream>>>(Qb, Kb, Vtb, Ob);

    // 4. wo fp32 -> bf16 into Kb (dead after attn)
    f32_to_bf16<<<512, 256, 0, stream>>>(wo, Wob, (int)(WD / 8));

    // 5. output projection -> fp32 d_out; (64,4) = 256 blocks = 1 round
    gemm8p<float><<<dim3(64, 4), 512, 0, stream>>>(
        Ob, Wob, Wob, Wob, out, out, nullptr, 1024, 1.0f);
}

// Round 10
// 239.666 us; speedup vs baseline: 1.0637x; 1.0637x over previous
//
#include <hip/hip_runtime.h>
#include <type_traits>

// ============================================================================
// MHA: B=4, S=2048, D=1024, H=16, hd=64. fp32 I/O, bf16 MFMA compute.
// Round 18: consolidation. (a) GEMMs reverted to the R11/R13 ring (best
//   measured QKV 70.4us). R17's race-fixed faithful phase-split measured
//   79.8us @ MfmaUtil 24% — closes the phase-split class on this problem:
//   {2-phase 73.6, RING 70.4, BM256 80.7, 1-barrier-8wave 74.8, phase-split
//   79.8}. At K=1024 with 1 block/CU the deep schedule loses to the simple
//   counted ring at 3 blocks/CU. (b) Dispatch-count reduction: wo-bf16
//   conversion fused into cvt_xw (5 -> 4 dispatches). Blocked before only
//   by buffer lifetime (Wob aliased Kb which holds K until attn). Now wo
//   goes to Xb+MD (ws offset 64MB) when ws_size >= 66MB (runtime guard;
//   fallback = old separate dispatch, zero risk). Budget analysis: best
//   kernel times sum to ~190 of 242.6us -> ~50us lives in dispatch gaps/
//   tails; this removes one boundary.
// Kept (counter-verified): attn8 (8-wave shared staging, 2 blocks/CU,
// balanced CU pairing, 242.6us config), ring gemm (3-slot counted vmcnt(4),
// 0-conflict swizzle), global_load_lds staging, fused V-transpose, S^T
// packed P-stores, no-max softmax, Q pre-scale, raw v_exp_f32.
// Fragment layouts (m89/m91-verified):
//    A-frag:  A[m = lane&15][k = (lane>>4)*8 + j]
//    B-frag:  B[n = lane&15][k = (lane>>4)*8 + j]
//    C/D:     C[row(m) = (lane>>4)*4 + reg][col(n) = lane&15]
// ============================================================================

typedef unsigned short u16;
typedef __attribute__((ext_vector_type(8))) short s8;   // 8 bf16 (16B)
typedef __attribute__((ext_vector_type(4))) float f4;

#if __has_builtin(__builtin_amdgcn_exp2f)
#define EXP2(x) __builtin_amdgcn_exp2f(x)   // raw v_exp_f32, no ocml wrapper
#else
#define EXP2(x) exp2f(x)
#endif

__device__ __forceinline__ u16 f2bf(float f) {
    union { float f; unsigned u; } v; v.f = f;
    unsigned r = v.u + 0x7fffu + ((v.u >> 16) & 1u);   // RNE
    return (u16)(r >> 16);
}

// pack two fp32 -> two bf16 (truncation) in one v_perm: low u16 = a, high = b
__device__ __forceinline__ unsigned pack_bf2(float a, float b) {
    return __builtin_amdgcn_perm(__float_as_uint(b), __float_as_uint(a),
                                 0x07060302u);
}

// async 16B global -> LDS (wave-uniform lds base; HW scatters lane*16)
__device__ __forceinline__ void cp16(const void* g, void* l) {
    __builtin_amdgcn_global_load_lds(
        (const __attribute__((address_space(1))) unsigned int*)g,
        (__attribute__((address_space(3))) unsigned int*)l, 16, 0, 0);
}

__device__ __forceinline__ s8 load8f(const float* p) {
    const float4 lo = *(const float4*)p;
    const float4 hi = *(const float4*)(p + 4);
    s8 r;
    r[0] = (short)f2bf(lo.x); r[1] = (short)f2bf(lo.y);
    r[2] = (short)f2bf(lo.z); r[3] = (short)f2bf(lo.w);
    r[4] = (short)f2bf(hi.x); r[5] = (short)f2bf(hi.y);
    r[6] = (short)f2bf(hi.z); r[7] = (short)f2bf(hi.w);
    return r;
}

// ---------------------------------------------------------------------------
// fp32 -> bf16 bulk convert (RNE), n8 groups of 8 (fallback path only)
// ---------------------------------------------------------------------------
__global__ __launch_bounds__(256)
void f32_to_bf16(const float* __restrict__ in, u16* __restrict__ out, int n8)
{
    const int i = blockIdx.x * 256 + threadIdx.x;
    if (i < n8) *(s8*)(out + (size_t)i * 8) = load8f(in + (size_t)i * 8);
}

// fused conversion: x (4096 blocks) + wq/wk/wv (1536 blocks) + optionally wo
// (512 blocks; only when grid = 6144). All ranges block-aligned (no per-lane
// divergence). x: 1048576 g8; weights: 3 x 131072 g8; wo: 131072 g8.
__global__ __launch_bounds__(256)
void cvt_xw(const float* __restrict__ x,
            const float* __restrict__ wq, const float* __restrict__ wk,
            const float* __restrict__ wv, const float* __restrict__ wo,
            u16* __restrict__ Xb, u16* __restrict__ Wqkv,
            u16* __restrict__ Wob)
{
    const int i = blockIdx.x * 256 + threadIdx.x;
    if (i < 1048576) {
        *(s8*)(Xb + (size_t)i * 8) = load8f(x + (size_t)i * 8);
    } else if (i < 1048576 + 393216) {
        const int j = i - 1048576;
        const int sel = j >> 17;            // 0..2 (131072 = 2^17 groups)
        const int wi  = j & 131071;
        const float* src = (sel == 0) ? wq : ((sel == 1) ? wk : wv);
        *(s8*)(Wqkv + (size_t)sel * 1048576 + (size_t)wi * 8) =
            load8f(src + (size_t)wi * 8);
    } else {
        const int wi = i - 1441792;         // 0..131071
        *(s8*)(Wob + (size_t)wi * 8) = load8f(wo + (size_t)wi * 8);
    }
}

// ---------------------------------------------------------------------------
// C = A @ W^T, all-bf16, async staging, 3-slot counted-vmcnt pipeline (R11).
// A: [M,K] bf16. W per 128-col block from {W0,W1,W2} ([1024,K] bf16).
// n-range 0: C0 row-major (TC), scaled by cscale. 1: C1 row-major (TC).
// 2: VT transposed per-head: VT[(b*16+h)*64+d][2048], b=row>>11, s=row&2047.
// LDS: unpadded 128x32 per slot, chunk swizzle LDS[r][c] = G[r][c^((r>>1)&3)].
// ---------------------------------------------------------------------------
template<typename TC>
__global__ __launch_bounds__(256)
void gemm_bb(const u16* __restrict__ A,
             const u16* __restrict__ W0, const u16* __restrict__ W1,
             const u16* __restrict__ W2,
             TC* __restrict__ C0, TC* __restrict__ C1,
             u16* __restrict__ VT, int K, float cscale)
{
    __shared__ u16 As[3][128 * 32];
    __shared__ u16 Bs[3][128 * 32];

    const int t  = threadIdx.x;
    const int bm = blockIdx.x;
    const int nglob = blockIdx.y * 128;

    const u16* W; int nloc, mode;
    if (nglob < 1024)      { W = W0; nloc = nglob;        mode = 0; }
    else if (nglob < 2048) { W = W1; nloc = nglob - 1024; mode = 1; }
    else                   { W = W2; nloc = nglob - 2048; mode = 2; }

    const int lane = t & 63, w = t >> 6;
    const int wm = (w >> 1) * 64, wn = (w & 1) * 64;
    const int quad = lane >> 4, l16 = lane & 15;

    // staging: thread's global 16B chunk (swizzled), two 16-row issues each
    const int sc = (((lane & 3) ^ ((lane >> 3) & 3))) * 8;  // elem offset
    const int sr = w * 32 + (lane >> 2);                    // tile row, issue 0
    const u16* Ag0 = A + (size_t)(bm * 128 + sr) * K + sc;
    const u16* Ag1 = Ag0 + (size_t)16 * K;
    const u16* Wg0 = W + (size_t)(nloc + sr) * K + sc;
    const u16* Wg1 = Wg0 + (size_t)16 * K;
    const int la0 = (w * 32) * 32;        // wave-uniform LDS dest offsets
    const int la1 = (w * 32 + 16) * 32;

    // frag-read chunk offset (swizzle key from row bits [2:1] = l16 bits)
    const int ca = (quad ^ ((l16 >> 1) & 3)) * 8;

    auto stage = [&](int buf, int k0) {
        cp16(Ag0 + k0, &As[buf][la0]);
        cp16(Ag1 + k0, &As[buf][la1]);
        cp16(Wg0 + k0, &Bs[buf][la0]);
        cp16(Wg1 + k0, &Bs[buf][la1]);
    };

    f4 acc[4][4];
    for (int i = 0; i < 4; i++)
        for (int j = 0; j < 4; j++)
            acc[i][j] = (f4){0.f, 0.f, 0.f, 0.f};

    // prologue: tiles 0,1 in flight (8 outstanding loads per wave)
    stage(0, 0);
    stage(1, 32);
    int cur = 0;
    for (int k0 = 0; k0 < K; k0 += 32) {
        // tile t must be landed; leave tile t+1's 4 loads in flight.
        if (k0 + 32 < K) asm volatile("s_waitcnt vmcnt(4)" ::: "memory");
        else             asm volatile("s_waitcnt vmcnt(0)" ::: "memory");
        __builtin_amdgcn_s_barrier();
        // restage slot(t+2)%3 (= slot(t-1)): every wave finished reading it
        // during compute(t-1), which precedes this barrier in program order.
        if (k0 + 96 <= K) stage((cur + 2) % 3, k0 + 64);

        s8 af[4], bf[4];
        for (int i = 0; i < 4; i++)
            af[i] = *(const s8*)&As[cur][(wm + i * 16 + l16) * 32 + ca];
        for (int j = 0; j < 4; j++)
            bf[j] = *(const s8*)&Bs[cur][(wn + j * 16 + l16) * 32 + ca];
        for (int i = 0; i < 4; i++)
            for (int j = 0; j < 4; j++)
                acc[i][j] = __builtin_amdgcn_mfma_f32_16x16x32_bf16(
                                af[i], bf[j], acc[i][j], 0, 0, 0);
        cur = (cur == 2) ? 0 : cur + 1;
    }

    if (mode == 2) {
        // V -> Vt[(b*16+h)*64+d][s], 4 consecutive s per lane -> uint2
        for (int i = 0; i < 4; i++) {
            const int row0 = bm * 128 + wm + i * 16 + quad * 4;
            const int b = row0 >> 11, s = row0 & 2047;
            for (int j = 0; j < 4; j++) {
                const int n = nloc + wn + j * 16 + l16;   // 0..1023
                const int h = n >> 6, d = n & 63;
                unsigned lo = ((unsigned)f2bf(acc[i][j][1]) << 16) | f2bf(acc[i][j][0]);
                unsigned hi = ((unsigned)f2bf(acc[i][j][3]) << 16) | f2bf(acc[i][j][2]);
                *(uint2*)(VT + ((size_t)((b * 16 + h) * 64 + d)) * 2048 + s) =
                    make_uint2(lo, hi);
            }
        }
    } else {
        TC* C = (mode == 0) ? C0 : C1;
        const float cs = (mode == 0) ? cscale : 1.0f;
        for (int i = 0; i < 4; i++) {
            const int row = bm * 128 + wm + i * 16 + quad * 4;
            for (int j = 0; j < 4; j++) {
                const int col = nloc + wn + j * 16 + l16;
                for (int r = 0; r < 4; r++) {
                    const float val = acc[i][j][r] * cs;
                    if constexpr (std::is_same<TC, float>::value)
                        C[(size_t)(row + r) * 1024 + col] = val;
                    else
                        C[(size_t)(row + r) * 1024 + col] = f2bf(val);
                }
            }
        }
    }
}

// ---------------------------------------------------------------------------
// Flash-style causal attention, no-max softmax, one q32 granule per wave.
// Block: 512 threads = 8 waves sharing one K/V staging pipeline (2 cp16/
// wave/tile). Grid (64 bh, 8 y), p = y<4 ? 7-y : y-4 (heavy blocks first;
// (c, c+256) CU pairs sum to 36 staged tiles on every CU -> balanced).
// Wave w owns q32 = 8p+w; ktw = q32/2+1; block stages ktb = 4p+4 tiles.
// LDS 69.6KB -> 2 blocks/CU = 16 waves/CU. K/V dbuf; stage(kt+1) before
// compute(kt). Q,K: [B*S,1024] bf16 (Q pre-scaled by (1/8)log2e).
// Vt: [(b*16+h)*64+d][2048] bf16.  O -> Q's buffer (row/col disjoint, safe).
// ---------------------------------------------------------------------------
#define PSTR 72   // Ps row stride elems (144B: 16B-aligned rows)

__global__ __launch_bounds__(512)
void attn8(const u16* __restrict__ Q, const u16* __restrict__ K,
           const u16* __restrict__ Vt, u16* __restrict__ O)
{
    __shared__ u16 Ks[2][64 * 64];      // [s][d] swizzled, double-buffered
    __shared__ u16 Vs[2][64 * 64];      // [d][s] swizzled, double-buffered
    __shared__ u16 Ps[8][32 * PSTR];    // per-wave P [q(32)][kv(64)]

    const int bh = blockIdx.x;          // b*16 + h
    const int yy = blockIdx.y;          // 0..7
    const int p  = (yy < 4) ? (7 - yy) : (yy - 4);   // balanced CU pairing
    const int h  = bh & 15, b = bh >> 4;

    const int t = threadIdx.x, lane = t & 63, w = t >> 6;   // w: 0..7
    const int quad = lane >> 4, l16 = lane & 15;
    const int colH = h * 64;

    const int q32 = 8 * p + w;          // this wave's q granule 0..63
    const int ktw = q32 / 2 + 1;        // wave's kv tile count
    const int ktb = 4 * p + 4;          // block staging count (= max ktw)

    s8 ones;
    for (int e = 0; e < 8; e++) ones[e] = (short)0x3F80;   // bf16 1.0

    // staging coords: each wave stages 8 rows of K and 8 rows of V per tile
    const int vrow = lane >> 3;                    // 0..7
    const int scc  = ((lane & 7) ^ vrow) * 8;      // swizzled chunk
    const int r0   = w * 8 + vrow;                 // row 0..63
    const u16* Kg = K  + ((size_t)b * 2048 + r0) * 1024 + colH + scc;
    const u16* Vg = Vt + ((size_t)(b * 16 + h) * 64 + r0) * 2048 + scc;
    const int klds = (w * 8) * 64;      // wave-uniform LDS dest offset

    auto stageKV = [&](int buf, int kt) {
        cp16(Kg + (size_t)kt * 65536, &Ks[buf][klds]);
        cp16(Vg + kt * 64, &Vs[buf][klds]);
    };

    const size_t rowQ0 = (size_t)b * 2048 + q32 * 32;

    // Q fragments for this wave's 32 rows (A-layout, pre-scaled)
    s8 qf[2][2];
    for (int i = 0; i < 2; i++)
        for (int kk = 0; kk < 2; kk++)
            qf[i][kk] = *(const s8*)&Q[(rowQ0 + i * 16 + l16) * 1024 +
                                       colH + kk * 32 + quad * 8];

    f4 o_acc[2][4];
    f4 l_acc[2];
    for (int i = 0; i < 2; i++) {
        l_acc[i] = (f4){0.f, 0.f, 0.f, 0.f};
        for (int j = 0; j < 4; j++)
            o_acc[i][j] = (f4){0.f, 0.f, 0.f, 0.f};
    }

    stageKV(0, 0);                      // prologue: tile 0 in flight
    int cur = 0;

    for (int kt = 0; kt < ktb; ++kt) {
        __syncthreads();                      // buf[cur] DMA done;
                                              // prev reads of buf^1 done
        if (kt + 1 < ktb) stageKV(cur ^ 1, kt + 1);   // next in flight

        if (kt < ktw) {
            // S^T = K @ Q^T : sa[j][i] kv on C/D rows, q on cols
            f4 sa[4][2];
            for (int j = 0; j < 4; j++)
                for (int i = 0; i < 2; i++)
                    sa[j][i] = (f4){0.f, 0.f, 0.f, 0.f};
            for (int kk = 0; kk < 2; kk++) {
                s8 kf[4];
                for (int j = 0; j < 4; j++)
                    kf[j] = *(const s8*)&Ks[cur][(j * 16 + l16) * 64 +
                                            (((kk * 4 + quad) ^ (l16 & 7)) * 8)];
                for (int j = 0; j < 4; j++)
                    for (int i = 0; i < 2; i++)
                        sa[j][i] = __builtin_amdgcn_mfma_f32_16x16x32_bf16(
                                       kf[j], qf[i][kk], sa[j][i], 0, 0, 0);
            }

            // P = exp2(sa) via raw v_exp_f32; causal mask on last tile
            const bool diag = (kt == ktw - 1);
            for (int i = 0; i < 2; i++) {
                const int q_l = i * 16 + l16;               // local row
                const int q_g = q32 * 32 + q_l;             // global row
                for (int j = 0; j < 4; j++) {
                    const int kv0 = kt * 64 + j * 16 + quad * 4;
                    float p0 = EXP2(sa[j][i][0]);
                    float p1 = EXP2(sa[j][i][1]);
                    float p2 = EXP2(sa[j][i][2]);
                    float p3 = EXP2(sa[j][i][3]);
                    if (diag) {
                        if (kv0 + 0 > q_g) p0 = 0.f;
                        if (kv0 + 1 > q_g) p1 = 0.f;
                        if (kv0 + 2 > q_g) p2 = 0.f;
                        if (kv0 + 3 > q_g) p3 = 0.f;
                    }
                    *(uint2*)&Ps[w][q_l * PSTR + j * 16 + quad * 4] =
                        make_uint2(pack_bf2(p0, p1), pack_bf2(p2, p3));
                }
            }
            // no barrier: Ps[w] wave-private; per-wave DS ops in order

            // O += P @ V ; l += P @ ones
            for (int kk = 0; kk < 2; kk++) {
                s8 pf[2], vf[4];
                for (int i = 0; i < 2; i++)
                    pf[i] = *(const s8*)&Ps[w][(i * 16 + l16) * PSTR +
                                               kk * 32 + quad * 8];
                for (int jd = 0; jd < 4; jd++)
                    vf[jd] = *(const s8*)&Vs[cur][(jd * 16 + l16) * 64 +
                                            (((kk * 4 + quad) ^ (l16 & 7)) * 8)];
                for (int i = 0; i < 2; i++)
                    l_acc[i] = __builtin_amdgcn_mfma_f32_16x16x32_bf16(
                                   pf[i], ones, l_acc[i], 0, 0, 0);
                for (int i = 0; i < 2; i++)
                    for (int jd = 0; jd < 4; jd++)
                        o_acc[i][jd] = __builtin_amdgcn_mfma_f32_16x16x32_bf16(
                                           pf[i], vf[jd], o_acc[i][jd], 0, 0, 0);
            }
        }
        cur ^= 1;
    }

    // epilogue: O /= l, write 32 rows (disjoint rows/cols -> safe to alias
    // Q: only this wave ever touches rows q32*32.. at cols colH..)
    for (int i = 0; i < 2; i++) {
        float rinv[4];
        for (int r = 0; r < 4; r++) rinv[r] = 1.0f / l_acc[i][r];
        for (int jd = 0; jd < 4; jd++)
            for (int r = 0; r < 4; r++) {
                const size_t row = rowQ0 + i * 16 + quad * 4 + r;
                O[row * 1024 + colH + jd * 16 + l16] =
                    f2bf(o_acc[i][jd][r] * rinv[r]);
            }
    }
}

// ---------------------------------------------------------------------------
extern "C" void kernel_launch(void* const* d_in, const int* in_sizes, int n_in,
                              void* d_out, int out_size, void* d_ws, size_t ws_size,
                              hipStream_t stream)
{
    const float* x  = (const float*)d_in[0];
    const float* wq = (const float*)d_in[1];
    const float* wk = (const float*)d_in[2];
    const float* wv = (const float*)d_in[3];
    const float* wo = (const float*)d_in[4];
    float* out = (float*)d_out;

    const size_t MD = (size_t)8192 * 1024;
    const size_t WD = (size_t)1024 * 1024;
    u16* Qb  = (u16*)d_ws;       // Q, later O
    u16* Kb  = Qb + MD;          // K, later (fallback) wo-bf16
    u16* Vtb = Kb + MD;          // V transposed
    u16* Xb  = Vtb + MD;         // x bf16
    u16* Wqkv = (u16*)d_out;     // wq/wk/wv bf16 scratch (dead before gemm2)
    u16* Ob  = Qb;

    // wo-bf16 home: ws tail (fused path) if workspace allows, else Kb after
    // attn (fallback, separate dispatch).
    const bool fuse_wo = ws_size >= (size_t)(4 * MD + WD) * sizeof(u16);
    u16* Wob = fuse_wo ? (Xb + MD) : Kb;

    // 1. fused conversion: x -> Xb, {wq,wk,wv} -> Wqkv, [wo -> Wob]
    cvt_xw<<<fuse_wo ? 6144 : 5632, 256, 0, stream>>>(
        x, wq, wk, wv, wo, Xb, Wqkv, Wob);

    // 2. QKV projections (V written transposed; Q scaled by (1/8)log2e)
    gemm_bb<u16><<<dim3(64, 24), 256, 0, stream>>>(
        Xb, Wqkv, Wqkv + WD, Wqkv + 2 * WD, Qb, Kb, Vtb, 1024, 0.18033688f);

    // 3. causal attention (O -> Qb); grid (bh, y): same-bh blocks same XCD
    attn8<<<dim3(64, 8), 512, 0, stream>>>(Qb, Kb, Vtb, Ob);

    // 4. (fallback only) wo fp32 -> bf16 into Kb (dead after attn)
    if (!fuse_wo)
        f32_to_bf16<<<512, 256, 0, stream>>>(wo, Wob, (int)(WD / 8));

    // 5. output projection -> fp32 d_out (overwrites dead W scratch)
    gemm_bb<float><<<dim3(64, 8), 256, 0, stream>>>(
        Ob, Wob, Wob, Wob, out, out, nullptr, 1024, 1.0f);
}